// Round 9
// baseline (273.666 us; speedup 1.0000x reference)
//
#include <hip/hip_runtime.h>
#include <hip/hip_bf16.h>

#define B_ 4
#define T_ 2048
#define C_ 1024
#define H_ 16
#define D_ 64
#define SCALE_ 0.125f
#define L2E 1.4426950408889634f
#define SE (SCALE_ * L2E)

typedef __attribute__((ext_vector_type(8))) short bf16x8;
typedef __attribute__((ext_vector_type(4))) float f32x4;

__device__ __forceinline__ unsigned short f2bf(float f) {
    union { float f; unsigned u; } v; v.f = f;
    unsigned r = v.u + 0x7fff + ((v.u >> 16) & 1);
    return (unsigned short)(r >> 16);
}

__device__ __forceinline__ unsigned pk2bf(float a, float b) {
    __hip_bfloat162 t = __float22bfloat162_rn(make_float2(a, b));
    union { __hip_bfloat162 h; unsigned u; } c; c.h = t;
    return c.u;
}

__device__ __forceinline__ void gl_lds16(const unsigned short* g, unsigned short* l) {
    __builtin_amdgcn_global_load_lds(
        (const __attribute__((address_space(1))) void*)g,
        (__attribute__((address_space(3))) void*)l,
        16, 0, 0);
}

// barrier WITH compiler memory fence, WITHOUT waitcnt drain.
__device__ __forceinline__ void bar_fence() {
    asm volatile("s_barrier" ::: "memory");
}

// ---------------- kernel 1: fused hs fp32->bf16 convert + weight transpose ----
__global__ void cvtw_kernel(const float4* __restrict__ in, ushort4* __restrict__ out,
                            const float* __restrict__ Wq, const float* __restrict__ Wk,
                            const float* __restrict__ Wv, const float* __restrict__ Wo,
                            unsigned short* __restrict__ Wqkv_t, unsigned short* __restrict__ Wo_t) {
    __shared__ float tile[64][65];
    const int bid = blockIdx.x;
    const int t = threadIdx.x;
    if (bid < 8192) {
        int i = bid * 256 + t;
        float4 v = in[i];
        ushort4 o;
        o.x = f2bf(v.x); o.y = f2bf(v.y); o.z = f2bf(v.z); o.w = f2bf(v.w);
        out[i] = o;
        return;
    }
    const int wb = bid - 8192;
    const int mtx = wb >> 8;
    const float* W = (mtx == 0) ? Wq : (mtx == 1) ? Wk : (mtx == 2) ? Wv : Wo;
    unsigned short* Out = (mtx < 3) ? (Wqkv_t + (size_t)mtx * 1024 * 1024) : Wo_t;
    const int tl = wb & 255;
    const int tx = tl & 15, ty = tl >> 4;
    const int col = t & 63, rb = t >> 6;
#pragma unroll
    for (int rr = 0; rr < 16; ++rr) {
        int r = rb * 16 + rr;
        tile[r][col] = W[(size_t)(ty * 64 + r) * 1024 + tx * 64 + col];
    }
    __syncthreads();
#pragma unroll
    for (int rr = 0; rr < 16; ++rr) {
        int r = rb * 16 + rr;
        Out[(size_t)(tx * 64 + r) * 1024 + ty * 64 + col] = f2bf(tile[col][r]);
    }
}

// ---------------- shared 128x128-tile GEMM machinery ---------------------------
// Round-8 post-mortem: 128x256 tile (96KB LDS) = 1 block/CU -> every per-K-tile
// vmcnt(0)+barrier is a whole-CU stall (no co-resident block to hide it; m114's
// cross-block overlap is the m97 structure's actual win). Fix: BM=BN=128, BK=64
// -> LDS 64KB -> 2 blocks/CU, 4 waves/SIMD; qkv grid 1536 = 3 tail-free rounds
// at 2/CU, gemm_out grid 512 = 1 round. Per-wave tile 64x32, acc[4][2] (32
// VGPR) under __launch_bounds__(512,4). Staging + T2 both-sides swizzle formulas
// byte-identical to the round-7-verified ones.
__device__ __forceinline__ void stage_panel16k(
    const unsigned short* __restrict__ G, unsigned short* Ldst,
    int kt, int row0, int tid) {
    // stages [128 rows][64 cols] bf16 = 16KB into Ldst, inverse-swizzled source
#pragma unroll
    for (int i = 0; i < 2; ++i) {
        int idx = i * 512 + tid;
        int r = idx >> 3;
        int c2 = ((idx & 7) * 16) ^ ((r & 7) << 4);
        gl_lds16(G + (size_t)(row0 + r) * 1024 + kt * 64 + (c2 >> 1),
                 Ldst + idx * 8);
    }
}

// fills acc[4][2] for this block's 128x128 tile; Lsh = 32768 shorts (64KB):
// A slots at 0/8192, B slots at 16384/24576.
__device__ __forceinline__ void gemm_128x128_loop(
    const unsigned short* __restrict__ A, const unsigned short* __restrict__ Bt,
    unsigned short* Lsh, f32x4 (&acc)[4][2],
    int m0, int n0, int tid, int wr, int wc, int quad, int l16) {
    // prologue: stage K-tile 0 into slot 0
    stage_panel16k(A, Lsh, 0, m0, tid);
    stage_panel16k(Bt, Lsh + 16384, 0, n0, tid);
    asm volatile("s_waitcnt vmcnt(0)" ::: "memory");
    bar_fence();

#pragma unroll 1
    for (int kt = 0; kt < 16; ++kt) {
        const int slot = kt & 1;
        // stage next K-tile into the other slot (wraps to tile 0 on last iter:
        // valid memory, never consumed)
        stage_panel16k(A, Lsh + (slot ^ 1) * 8192, (kt + 1) & 15, m0, tid);
        stage_panel16k(Bt, Lsh + 16384 + (slot ^ 1) * 8192, (kt + 1) & 15, n0, tid);

#pragma unroll
        for (int ks = 0; ks < 2; ++ks) {
            bf16x8 a[4], b[2];
#pragma unroll
            for (int i = 0; i < 4; ++i) {
                int r = wr * 64 + i * 16 + l16;
                int cb = (ks * 64 + quad * 16) ^ ((r & 7) << 4);
                a[i] = *(const bf16x8*)(Lsh + slot * 8192 + r * 64 + (cb >> 1));
            }
#pragma unroll
            for (int j = 0; j < 2; ++j) {
                int r = wc * 32 + j * 16 + l16;
                int cb = (ks * 64 + quad * 16) ^ ((r & 7) << 4);
                b[j] = *(const bf16x8*)(Lsh + 16384 + slot * 8192 + r * 64 + (cb >> 1));
            }
            __builtin_amdgcn_s_setprio(1);
#pragma unroll
            for (int i = 0; i < 4; ++i)
#pragma unroll
                for (int j = 0; j < 2; ++j)
                    acc[i][j] = __builtin_amdgcn_mfma_f32_16x16x32_bf16(a[i], b[j], acc[i][j], 0, 0, 0);
            __builtin_amdgcn_s_setprio(0);
        }
        asm volatile("s_waitcnt vmcnt(0)" ::: "memory");
        bar_fence();
    }
}

// ---------------- kernel 3: QKV GEMM (8192x1024 @ 1024x3072) ----------------
// grid 1536 = 8 xcd x 192 = 3 tail-free rounds at 2 blocks/CU.
__global__ __launch_bounds__(512, 4) void gemm_qkv_kernel(
    const unsigned short* __restrict__ A, const unsigned short* __restrict__ Bt,
    unsigned short* __restrict__ Qg, unsigned short* __restrict__ Kf, unsigned short* __restrict__ Vf) {
    __shared__ __align__(16) unsigned short Lsh[32768];   // 64 KB

    const int tid = threadIdx.x;
    const int w = tid >> 6, lane = tid & 63;
    const int quad = lane >> 4, l16 = lane & 15;
    const int wr = w >> 2, wc = w & 3;                    // 2(M) x 4(N) wave grid
    const int bid = blockIdx.x;
    const int swz = (bid & 7) * 192 + (bid >> 3);
    const int m0 = (swz & 63) * 128, n0 = (swz >> 6) * 128;

    const f32x4 fzero = {0.f, 0.f, 0.f, 0.f};
    f32x4 acc[4][2];
#pragma unroll
    for (int i = 0; i < 4; ++i)
#pragma unroll
        for (int j = 0; j < 2; ++j) acc[i][j] = fzero;

    gemm_128x128_loop(A, Bt, Lsh, acc, m0, n0, tid, wr, wc, quad, l16);

    // epilogue: scatter to Q/K/V layouts.  acc[i][j]:
    // row = m0 + wr*64 + i*16 + quad*4 + r ; col = n0 + wc*32 + j*16 + l16
#pragma unroll
    for (int j = 0; j < 2; ++j) {
        int gn = n0 + wc * 32 + j * 16 + l16;
        int tensor = gn >> 10;
        int nl = gn & 1023;
        int hh = nl >> 6, dd = nl & 63;
#pragma unroll
        for (int i = 0; i < 4; ++i) {
            int gmb = m0 + wr * 64 + i * 16 + quad * 4;
            int bb = gmb >> 11;
            size_t bhh = (size_t)(bb * 16 + hh);
            if (tensor == 0) {
#pragma unroll
                for (int r = 0; r < 4; ++r) {
                    int tt = (gmb + r) & 2047;
                    Qg[(bhh * 2048 + tt) * 64 + dd] = f2bf(acc[i][j][r] * SE);
                }
            } else if (tensor == 1) {
#pragma unroll
                for (int r = 0; r < 4; ++r) {
                    int tt = (gmb + r) & 2047;
                    Kf[bhh * 131072 + (size_t)(tt >> 4) * 1024 + (dd >> 5) * 512 +
                       (((dd >> 3) & 3) * 16 + (tt & 15)) * 8 + (dd & 7)] = f2bf(acc[i][j][r]);
                }
            } else {
                int tt = gmb & 2047;
                ushort4 v4;
                v4.x = f2bf(acc[i][j][0]); v4.y = f2bf(acc[i][j][1]);
                v4.z = f2bf(acc[i][j][2]); v4.w = f2bf(acc[i][j][3]);
                *(ushort4*)(Vf + bhh * 131072 + (size_t)(tt >> 5) * 2048 + (dd >> 4) * 512 +
                            (((tt >> 3) & 3) * 16 + (dd & 15)) * 8 + (tt & 7)) = v4;
            }
        }
    }
}

// ---------------- kernel 5: output GEMM (8192x1024 @ 1024x1024) + bias --------
// grid 512 = 8 xcd x 64 = EXACTLY 1 tail-free round at 2 blocks/CU.
__global__ __launch_bounds__(512, 4) void gemm_out_kernel(
    const unsigned short* __restrict__ A, const unsigned short* __restrict__ Bt,
    const float* __restrict__ bo, float* __restrict__ out) {
    __shared__ __align__(16) unsigned short Lsh[32768];   // 64 KB

    const int tid = threadIdx.x;
    const int w = tid >> 6, lane = tid & 63;
    const int quad = lane >> 4, l16 = lane & 15;
    const int wr = w >> 2, wc = w & 3;
    const int bid = blockIdx.x;
    const int swz = (bid & 7) * 64 + (bid >> 3);
    const int m0 = (swz & 63) * 128, n0 = (swz >> 6) * 128;

    const f32x4 fzero = {0.f, 0.f, 0.f, 0.f};
    f32x4 acc[4][2];
#pragma unroll
    for (int i = 0; i < 4; ++i)
#pragma unroll
        for (int j = 0; j < 2; ++j) acc[i][j] = fzero;

    gemm_128x128_loop(A, Bt, Lsh, acc, m0, n0, tid, wr, wc, quad, l16);

#pragma unroll
    for (int j = 0; j < 2; ++j) {
        int gn = n0 + wc * 32 + j * 16 + l16;
        float bias = bo[gn];
#pragma unroll
        for (int i = 0; i < 4; ++i) {
            int gmb = m0 + wr * 64 + i * 16 + quad * 4;
#pragma unroll
            for (int r = 0; r < 4; ++r)
                out[(size_t)(gmb + r) * 1024 + gn] = acc[i][j][r] + bias;
        }
    }
}

// ---------------- kernel 4: flash attention (LDS-staged K/V, 8 waves/block) ----
// EXACT round-2 structure (87.6us verified).  V fragment reads must stay AFTER
// the P-write section (round-3 lesson: hoisting spills to scratch).
__device__ __forceinline__ void attn_step_staged(
    int k0, const unsigned short* Kc, const unsigned short* Vc,
    unsigned short* Kn, unsigned short* Vn, int kn0,
    const unsigned short* __restrict__ Kg, const unsigned short* __restrict__ Vg,
    unsigned short* Pw, const bf16x8 (&aq)[2][2], const bf16x8& vones,
    f32x4 (&po)[2][4], f32x4 (&pl)[2],
    const int* __restrict__ mrow, int w, int lane, int quad, int l16) {

    gl_lds16(Kg + (size_t)(kn0 >> 4) * 1024 + w * 512 + lane * 8, Kn + w * 512);
    gl_lds16(Vg + (size_t)(kn0 >> 5) * 2048 + w * 512 + lane * 8, Vn + w * 512);

    bf16x8 ka0[4], ka1[4];
#pragma unroll
    for (int kt = 0; kt < 4; ++kt) {
        ka0[kt] = *(const bf16x8*)(Kc + kt * 1024 + lane * 8);
        ka1[kt] = *(const bf16x8*)(Kc + kt * 1024 + 512 + lane * 8);
    }

    const f32x4 fzero = {0.f, 0.f, 0.f, 0.f};
    int mk = mrow[k0 + lane];
    bool allok = (__ballot(mk != 0) == 0xFFFFFFFFFFFFFFFFull);

    if (allok) {
#pragma unroll
        for (int kt = 0; kt < 4; ++kt) {
            int pidx = ((((kt & 1) << 1) | (quad >> 1)) * 16 + l16) * 8 + (quad & 1) * 4;
#pragma unroll
            for (int qi = 0; qi < 2; ++qi) {
                f32x4 st = __builtin_amdgcn_mfma_f32_16x16x32_bf16(ka0[kt], aq[qi][0], fzero, 0, 0, 0);
                st = __builtin_amdgcn_mfma_f32_16x16x32_bf16(ka1[kt], aq[qi][1], st, 0, 0, 0);
                float p0 = __builtin_amdgcn_exp2f(st[0]);
                float p1 = __builtin_amdgcn_exp2f(st[1]);
                float p2 = __builtin_amdgcn_exp2f(st[2]);
                float p3 = __builtin_amdgcn_exp2f(st[3]);
                uint2 pk; pk.x = pk2bf(p0, p1); pk.y = pk2bf(p2, p3);
                *(uint2*)(Pw + (qi * 2 + (kt >> 1)) * 512 + pidx) = pk;
            }
        }
    } else {
#pragma unroll
        for (int kt = 0; kt < 4; ++kt) {
            int4 mv = *(const int4*)(mrow + k0 + kt * 16 + quad * 4);
            float mb0 = mv.x ? 0.f : -1e30f;
            float mb1 = mv.y ? 0.f : -1e30f;
            float mb2 = mv.z ? 0.f : -1e30f;
            float mb3 = mv.w ? 0.f : -1e30f;
            int pidx = ((((kt & 1) << 1) | (quad >> 1)) * 16 + l16) * 8 + (quad & 1) * 4;
#pragma unroll
            for (int qi = 0; qi < 2; ++qi) {
                f32x4 st = __builtin_amdgcn_mfma_f32_16x16x32_bf16(ka0[kt], aq[qi][0], fzero, 0, 0, 0);
                st = __builtin_amdgcn_mfma_f32_16x16x32_bf16(ka1[kt], aq[qi][1], st, 0, 0, 0);
                float p0 = __builtin_amdgcn_exp2f(st[0] + mb0);
                float p1 = __builtin_amdgcn_exp2f(st[1] + mb1);
                float p2 = __builtin_amdgcn_exp2f(st[2] + mb2);
                float p3 = __builtin_amdgcn_exp2f(st[3] + mb3);
                uint2 pk; pk.x = pk2bf(p0, p1); pk.y = pk2bf(p2, p3);
                *(uint2*)(Pw + (qi * 2 + (kt >> 1)) * 512 + pidx) = pk;
            }
        }
    }

    bf16x8 bv[2][4];
#pragma unroll
    for (int c = 0; c < 2; ++c)
#pragma unroll
        for (int nd = 0; nd < 4; ++nd)
            bv[c][nd] = *(const bf16x8*)(Vc + c * 2048 + nd * 512 + lane * 8);

    asm volatile("s_waitcnt lgkmcnt(0)" ::: "memory");

#pragma unroll
    for (int c = 0; c < 2; ++c)
#pragma unroll
        for (int qi = 0; qi < 2; ++qi) {
            bf16x8 ap = *(const bf16x8*)(Pw + (qi * 2 + c) * 512 + lane * 8);
#pragma unroll
            for (int nd = 0; nd < 4; ++nd)
                po[qi][nd] = __builtin_amdgcn_mfma_f32_16x16x32_bf16(ap, bv[c][nd], po[qi][nd], 0, 0, 0);
            pl[qi] = __builtin_amdgcn_mfma_f32_16x16x32_bf16(ap, vones, pl[qi], 0, 0, 0);
        }
}

__global__ __launch_bounds__(512, 4) void attn_kernel(
    const unsigned short* __restrict__ Qg, const unsigned short* __restrict__ Kf,
    const unsigned short* __restrict__ Vf, const int* __restrict__ mask,
    unsigned short* __restrict__ AO) {
    __shared__ __align__(16) unsigned short KsA[4096], KsB[4096];
    __shared__ __align__(16) unsigned short VsA[4096], VsB[4096];
    __shared__ __align__(16) unsigned short Pbuf[8][2048];

    const int tid = threadIdx.x;
    const int w = tid >> 6, lane = tid & 63;
    const int quad = lane >> 4, l16 = lane & 15;
    const int bid = blockIdx.x;
    const int bh = (bid & 7) * 8 + ((bid >> 6) & 7);
    const int qt = (bid >> 3) & 7;
    const int b = bh >> 4, h = bh & 15;
    const size_t bh_td = (size_t)bh * (2048 * 64);
    const int q0w = qt * 256 + w * 32;

    bf16x8 aq[2][2];
#pragma unroll
    for (int qi = 0; qi < 2; ++qi)
#pragma unroll
        for (int hh = 0; hh < 2; ++hh)
            aq[qi][hh] = *(const bf16x8*)(Qg + bh_td + (size_t)(q0w + qi * 16 + l16) * 64 + hh * 32 + quad * 8);

    const unsigned short* Kg = Kf + bh_td;
    const unsigned short* Vg = Vf + bh_td;
    const int* mrow = mask + b * 2048;

    bf16x8 vones;
#pragma unroll
    for (int i = 0; i < 8; ++i) vones[i] = (short)0x3F80;

    const f32x4 fzero = {0.f, 0.f, 0.f, 0.f};
    f32x4 po[2][4];
    f32x4 pl[2];
#pragma unroll
    for (int qi = 0; qi < 2; ++qi) {
        pl[qi] = fzero;
#pragma unroll
        for (int nd = 0; nd < 4; ++nd) po[qi][nd] = fzero;
    }

    gl_lds16(Kg + w * 512 + lane * 8, KsA + w * 512);
    gl_lds16(Vg + w * 512 + lane * 8, VsA + w * 512);
    asm volatile("s_waitcnt vmcnt(0)" ::: "memory");
    __syncthreads();

#pragma unroll 1
    for (int k0 = 0; k0 < 2048; k0 += 128) {
        attn_step_staged(k0, KsA, VsA, KsB, VsB, k0 + 64,
                         Kg, Vg, Pbuf[w], aq, vones, po, pl, mrow, w, lane, quad, l16);
        asm volatile("s_waitcnt vmcnt(0)" ::: "memory");
        __syncthreads();
        attn_step_staged(k0 + 64, KsB, VsB, KsA, VsA, (k0 + 128) & 2047,
                         Kg, Vg, Pbuf[w], aq, vones, po, pl, mrow, w, lane, quad, l16);
        asm volatile("s_waitcnt vmcnt(0)" ::: "memory");
        __syncthreads();
    }

#pragma unroll
    for (int qi = 0; qi < 2; ++qi)
#pragma unroll
        for (int r = 0; r < 4; ++r) {
            float linv = __builtin_amdgcn_rcpf(pl[qi][r]);
            int q = q0w + qi * 16 + quad * 4 + r;
            size_t ob = (size_t)(b * 2048 + q) * 1024 + h * 64;
#pragma unroll
            for (int nd = 0; nd < 4; ++nd)
                AO[ob + nd * 16 + l16] = f2bf(po[qi][nd][r] * linv);
        }
}

extern "C" void kernel_launch(void* const* d_in, const int* in_sizes, int n_in,
                              void* d_out, int out_size, void* d_ws, size_t ws_size,
                              hipStream_t stream) {
    const float* hs  = (const float*)d_in[0];
    const int* mask  = (const int*)d_in[1];
    const float* Wq  = (const float*)d_in[2];
    const float* Wk  = (const float*)d_in[3];
    const float* Wv  = (const float*)d_in[4];
    const float* Wo  = (const float*)d_in[5];
    const float* bo  = (const float*)d_in[6];
    float* out = (float*)d_out;

    char* ws = (char*)d_ws;
    unsigned short* hs_bf = (unsigned short*)(ws);                  // 16 MB
    unsigned short* wqkv  = (unsigned short*)(ws + 16777216);       // 6 MB
    unsigned short* wo_t  = (unsigned short*)(ws + 23068672);       // 2 MB
    unsigned short* Qg    = (unsigned short*)(ws + 25165824);       // 16 MB
    unsigned short* Kf    = (unsigned short*)(ws + 41943040);       // 16 MB
    unsigned short* Vf    = (unsigned short*)(ws + 58720256);       // 16 MB
    unsigned short* AO    = (unsigned short*)(ws + 75497472);       // 16 MB

    cvtw_kernel<<<9216, 256, 0, stream>>>((const float4*)hs, (ushort4*)hs_bf,
                                          Wq, Wk, Wv, Wo, wqkv, wo_t);
    gemm_qkv_kernel<<<1536, 512, 0, stream>>>(hs_bf, wqkv, Qg, Kf, Vf);
    attn_kernel<<<512, 512, 0, stream>>>(Qg, Kf, Vf, mask, AO);
    gemm_out_kernel<<<512, 512, 0, stream>>>(AO, wo_t, bo, out);
}

// Round 10
// 267.130 us; speedup vs baseline: 1.0245x; 1.0245x over previous
//
#include <hip/hip_runtime.h>
#include <hip/hip_bf16.h>

#define B_ 4
#define T_ 2048
#define C_ 1024
#define H_ 16
#define D_ 64
#define SCALE_ 0.125f
#define L2E 1.4426950408889634f
#define SE (SCALE_ * L2E)

typedef __attribute__((ext_vector_type(8))) short bf16x8;
typedef __attribute__((ext_vector_type(4))) float f32x4;

__device__ __forceinline__ unsigned short f2bf(float f) {
    union { float f; unsigned u; } v; v.f = f;
    unsigned r = v.u + 0x7fff + ((v.u >> 16) & 1);
    return (unsigned short)(r >> 16);
}

__device__ __forceinline__ unsigned pk2bf(float a, float b) {
    __hip_bfloat162 t = __float22bfloat162_rn(make_float2(a, b));
    union { __hip_bfloat162 h; unsigned u; } c; c.h = t;
    return c.u;
}

__device__ __forceinline__ void gl_lds16(const unsigned short* g, unsigned short* l) {
    __builtin_amdgcn_global_load_lds(
        (const __attribute__((address_space(1))) void*)g,
        (__attribute__((address_space(3))) void*)l,
        16, 0, 0);
}

// barrier WITH compiler memory fence, WITHOUT waitcnt drain.
__device__ __forceinline__ void bar_fence() {
    asm volatile("s_barrier" ::: "memory");
}

// ---------------- kernel 1: fused hs fp32->bf16 convert + weight transpose ----
__global__ void cvtw_kernel(const float4* __restrict__ in, ushort4* __restrict__ out,
                            const float* __restrict__ Wq, const float* __restrict__ Wk,
                            const float* __restrict__ Wv, const float* __restrict__ Wo,
                            unsigned short* __restrict__ Wqkv_t, unsigned short* __restrict__ Wo_t) {
    __shared__ float tile[64][65];
    const int bid = blockIdx.x;
    const int t = threadIdx.x;
    if (bid < 8192) {
        int i = bid * 256 + t;
        float4 v = in[i];
        ushort4 o;
        o.x = f2bf(v.x); o.y = f2bf(v.y); o.z = f2bf(v.z); o.w = f2bf(v.w);
        out[i] = o;
        return;
    }
    const int wb = bid - 8192;
    const int mtx = wb >> 8;
    const float* W = (mtx == 0) ? Wq : (mtx == 1) ? Wk : (mtx == 2) ? Wv : Wo;
    unsigned short* Out = (mtx < 3) ? (Wqkv_t + (size_t)mtx * 1024 * 1024) : Wo_t;
    const int tl = wb & 255;
    const int tx = tl & 15, ty = tl >> 4;
    const int col = t & 63, rb = t >> 6;
#pragma unroll
    for (int rr = 0; rr < 16; ++rr) {
        int r = rb * 16 + rr;
        tile[r][col] = W[(size_t)(ty * 64 + r) * 1024 + tx * 64 + col];
    }
    __syncthreads();
#pragma unroll
    for (int rr = 0; rr < 16; ++rr) {
        int r = rb * 16 + rr;
        Out[(size_t)(tx * 64 + r) * 1024 + ty * 64 + col] = f2bf(tile[col][r]);
    }
}

// ---------------- shared 128x256-tile GEMM machinery (best measured: round 8) --
// BM=128, BN=256, BK=64, 8 waves of 64x64. LDS 96KB = dbuf x (A 16KB + B 32KB).
// T3-minimal: stage next slot, compute current, one vmcnt(0)+barrier per K-tile.
// T2 both-sides swizzle: LDS row r holds global cols (p*16)^((r&7)<<4) at byte
// pos p*16; reader XORs the same mask.
__device__ __forceinline__ void qkv_stage_A(
    const unsigned short* __restrict__ A, unsigned short* Lsh,
    int slot, int kt, int m0, int tid, int w) {
#pragma unroll
    for (int i = 0; i < 2; ++i) {
        int idx = i * 512 + tid;
        int r = idx >> 3;
        int c2 = ((idx & 7) * 16) ^ ((r & 7) << 4);
        gl_lds16(A + (size_t)(m0 + r) * 1024 + kt * 64 + (c2 >> 1),
                 Lsh + slot * 8192 + (i * 512 + w * 64) * 8);
    }
}

__device__ __forceinline__ void qkv_stage_B(
    const unsigned short* __restrict__ Bt, unsigned short* Lsh,
    int slot, int kt, int n0, int tid, int w) {
#pragma unroll
    for (int i = 0; i < 4; ++i) {
        int idx = i * 512 + tid;
        int r = idx >> 3;
        int c2 = ((idx & 7) * 16) ^ ((r & 7) << 4);
        gl_lds16(Bt + (size_t)(n0 + r) * 1024 + kt * 64 + (c2 >> 1),
                 Lsh + 16384 + slot * 16384 + (i * 512 + w * 64) * 8);
    }
}

__device__ __forceinline__ void gemm_128x256_loop(
    const unsigned short* __restrict__ A, const unsigned short* __restrict__ Bt,
    unsigned short* Lsh, f32x4 (&acc)[4][4],
    int m0, int n0, int tid, int w, int wr, int wc, int quad, int l16) {
    qkv_stage_A(A, Lsh, 0, 0, m0, tid, w);
    qkv_stage_B(Bt, Lsh, 0, 0, n0, tid, w);
    asm volatile("s_waitcnt vmcnt(0)" ::: "memory");
    bar_fence();

#pragma unroll 1
    for (int kt = 0; kt < 16; ++kt) {
        const int slot = kt & 1;
        qkv_stage_A(A, Lsh, slot ^ 1, (kt + 1) & 15, m0, tid, w);
        qkv_stage_B(Bt, Lsh, slot ^ 1, (kt + 1) & 15, n0, tid, w);

#pragma unroll
        for (int ks = 0; ks < 2; ++ks) {
            bf16x8 a[4], b[4];
#pragma unroll
            for (int i = 0; i < 4; ++i) {
                int r = wr * 64 + i * 16 + l16;
                int cb = (ks * 64 + quad * 16) ^ ((r & 7) << 4);
                a[i] = *(const bf16x8*)(Lsh + slot * 8192 + r * 64 + (cb >> 1));
            }
#pragma unroll
            for (int j = 0; j < 4; ++j) {
                int r = wc * 64 + j * 16 + l16;
                int cb = (ks * 64 + quad * 16) ^ ((r & 7) << 4);
                b[j] = *(const bf16x8*)(Lsh + 16384 + slot * 16384 + r * 64 + (cb >> 1));
            }
            __builtin_amdgcn_s_setprio(1);
#pragma unroll
            for (int i = 0; i < 4; ++i)
#pragma unroll
                for (int j = 0; j < 4; ++j)
                    acc[i][j] = __builtin_amdgcn_mfma_f32_16x16x32_bf16(a[i], b[j], acc[i][j], 0, 0, 0);
            __builtin_amdgcn_s_setprio(0);
        }
        asm volatile("s_waitcnt vmcnt(0)" ::: "memory");
        bar_fence();
    }
}

// ---------------- kernel 3: QKV GEMM (8192x1024 @ 1024x3072) ----------------
// grid 768 = 8 xcd x 96 = EXACTLY 3 tail-free 1-block/CU rounds.
__global__ __launch_bounds__(512, 2) void gemm_qkv_kernel(
    const unsigned short* __restrict__ A, const unsigned short* __restrict__ Bt,
    unsigned short* __restrict__ Qg, unsigned short* __restrict__ Kf, unsigned short* __restrict__ Vf) {
    __shared__ __align__(16) unsigned short Lsh[49152];   // 96 KB

    const int tid = threadIdx.x;
    const int w = tid >> 6, lane = tid & 63;
    const int quad = lane >> 4, l16 = lane & 15;
    const int wr = w >> 2, wc = w & 3;
    const int bid = blockIdx.x;
    const int swz = (bid & 7) * 96 + (bid >> 3);
    const int m0 = (swz & 63) * 128, n0 = (swz >> 6) * 256;

    const f32x4 fzero = {0.f, 0.f, 0.f, 0.f};
    f32x4 acc[4][4];
#pragma unroll
    for (int i = 0; i < 4; ++i)
#pragma unroll
        for (int j = 0; j < 4; ++j) acc[i][j] = fzero;

    gemm_128x256_loop(A, Bt, Lsh, acc, m0, n0, tid, w, wr, wc, quad, l16);

    // epilogue: scatter to Q/K/V layouts.  acc[i][j]:
    // row = m0 + wr*64 + i*16 + quad*4 + r ; col = n0 + wc*64 + j*16 + l16
#pragma unroll
    for (int j = 0; j < 4; ++j) {
        int gn = n0 + wc * 64 + j * 16 + l16;
        int tensor = gn >> 10;
        int nl = gn & 1023;
        int hh = nl >> 6, dd = nl & 63;
#pragma unroll
        for (int i = 0; i < 4; ++i) {
            int gmb = m0 + wr * 64 + i * 16 + quad * 4;
            int bb = gmb >> 11;
            size_t bhh = (size_t)(bb * 16 + hh);
            if (tensor == 0) {
#pragma unroll
                for (int r = 0; r < 4; ++r) {
                    int tt = (gmb + r) & 2047;
                    Qg[(bhh * 2048 + tt) * 64 + dd] = f2bf(acc[i][j][r] * SE);
                }
            } else if (tensor == 1) {
#pragma unroll
                for (int r = 0; r < 4; ++r) {
                    int tt = (gmb + r) & 2047;
                    Kf[bhh * 131072 + (size_t)(tt >> 4) * 1024 + (dd >> 5) * 512 +
                       (((dd >> 3) & 3) * 16 + (tt & 15)) * 8 + (dd & 7)] = f2bf(acc[i][j][r]);
                }
            } else {
                int tt = gmb & 2047;
                ushort4 v4;
                v4.x = f2bf(acc[i][j][0]); v4.y = f2bf(acc[i][j][1]);
                v4.z = f2bf(acc[i][j][2]); v4.w = f2bf(acc[i][j][3]);
                *(ushort4*)(Vf + bhh * 131072 + (size_t)(tt >> 5) * 2048 + (dd >> 4) * 512 +
                            (((tt >> 3) & 3) * 16 + (dd & 15)) * 8 + (tt & 7)) = v4;
            }
        }
    }
}

// ---------------- kernel 5: output GEMM (8192x1024 @ 1024x1024) + bias --------
// grid 256 = 8 xcd x 32 = EXACTLY 1 block/CU, one tail-free round.
__global__ __launch_bounds__(512, 2) void gemm_out_kernel(
    const unsigned short* __restrict__ A, const unsigned short* __restrict__ Bt,
    const float* __restrict__ bo, float* __restrict__ out) {
    __shared__ __align__(16) unsigned short Lsh[49152];   // 96 KB

    const int tid = threadIdx.x;
    const int w = tid >> 6, lane = tid & 63;
    const int quad = lane >> 4, l16 = lane & 15;
    const int wr = w >> 2, wc = w & 3;
    const int bid = blockIdx.x;
    const int swz = (bid & 7) * 32 + (bid >> 3);
    const int m0 = (swz & 63) * 128, n0 = (swz >> 6) * 256;

    const f32x4 fzero = {0.f, 0.f, 0.f, 0.f};
    f32x4 acc[4][4];
#pragma unroll
    for (int i = 0; i < 4; ++i)
#pragma unroll
        for (int j = 0; j < 4; ++j) acc[i][j] = fzero;

    gemm_128x256_loop(A, Bt, Lsh, acc, m0, n0, tid, w, wr, wc, quad, l16);

#pragma unroll
    for (int j = 0; j < 4; ++j) {
        int gn = n0 + wc * 64 + j * 16 + l16;
        float bias = bo[gn];
#pragma unroll
        for (int i = 0; i < 4; ++i) {
            int gmb = m0 + wr * 64 + i * 16 + quad * 4;
#pragma unroll
            for (int r = 0; r < 4; ++r)
                out[(size_t)(gmb + r) * 1024 + gn] = acc[i][j][r] + bias;
        }
    }
}

// ---------------- kernel 4: flash attention (LDS-staged K/V, 8 waves/block) ----
// Round-2 verified structure. NEW (round 10): whole-row mask precheck hoisted
// out of the loop -- when the entire row is unmasked (the common case), the
// fast loop instantiation never loads mrow / ballots / branches per step,
// removing ~250 cyc of L2-load->ballot->branch from every wave's serial chain
// per step. Masked rows fall back to the verified per-step-check loop.
// V fragment reads stay AFTER the P-write section (round-3 scratch-spill lesson).
template <bool CHECK_MASK>
__device__ __forceinline__ void attn_step_staged(
    int k0, const unsigned short* Kc, const unsigned short* Vc,
    unsigned short* Kn, unsigned short* Vn, int kn0,
    const unsigned short* __restrict__ Kg, const unsigned short* __restrict__ Vg,
    unsigned short* Pw, const bf16x8 (&aq)[2][2], const bf16x8& vones,
    f32x4 (&po)[2][4], f32x4 (&pl)[2],
    const int* __restrict__ mrow, int w, int lane, int quad, int l16) {

    gl_lds16(Kg + (size_t)(kn0 >> 4) * 1024 + w * 512 + lane * 8, Kn + w * 512);
    gl_lds16(Vg + (size_t)(kn0 >> 5) * 2048 + w * 512 + lane * 8, Vn + w * 512);

    bf16x8 ka0[4], ka1[4];
#pragma unroll
    for (int kt = 0; kt < 4; ++kt) {
        ka0[kt] = *(const bf16x8*)(Kc + kt * 1024 + lane * 8);
        ka1[kt] = *(const bf16x8*)(Kc + kt * 1024 + 512 + lane * 8);
    }

    const f32x4 fzero = {0.f, 0.f, 0.f, 0.f};
    bool allok = true;
    if (CHECK_MASK) {
        int mk = mrow[k0 + lane];
        allok = (__ballot(mk != 0) == 0xFFFFFFFFFFFFFFFFull);
    }

    if (allok) {
        // ---- fast path: p = exp2(st) directly ----
#pragma unroll
        for (int kt = 0; kt < 4; ++kt) {
            int pidx = ((((kt & 1) << 1) | (quad >> 1)) * 16 + l16) * 8 + (quad & 1) * 4;
#pragma unroll
            for (int qi = 0; qi < 2; ++qi) {
                f32x4 st = __builtin_amdgcn_mfma_f32_16x16x32_bf16(ka0[kt], aq[qi][0], fzero, 0, 0, 0);
                st = __builtin_amdgcn_mfma_f32_16x16x32_bf16(ka1[kt], aq[qi][1], st, 0, 0, 0);
                float p0 = __builtin_amdgcn_exp2f(st[0]);
                float p1 = __builtin_amdgcn_exp2f(st[1]);
                float p2 = __builtin_amdgcn_exp2f(st[2]);
                float p3 = __builtin_amdgcn_exp2f(st[3]);
                uint2 pk; pk.x = pk2bf(p0, p1); pk.y = pk2bf(p2, p3);
                *(uint2*)(Pw + (qi * 2 + (kt >> 1)) * 512 + pidx) = pk;
            }
        }
    } else {
        // ---- slow path: additive mask bias (only reachable when CHECK_MASK) ----
#pragma unroll
        for (int kt = 0; kt < 4; ++kt) {
            int4 mv = *(const int4*)(mrow + k0 + kt * 16 + quad * 4);
            float mb0 = mv.x ? 0.f : -1e30f;
            float mb1 = mv.y ? 0.f : -1e30f;
            float mb2 = mv.z ? 0.f : -1e30f;
            float mb3 = mv.w ? 0.f : -1e30f;
            int pidx = ((((kt & 1) << 1) | (quad >> 1)) * 16 + l16) * 8 + (quad & 1) * 4;
#pragma unroll
            for (int qi = 0; qi < 2; ++qi) {
                f32x4 st = __builtin_amdgcn_mfma_f32_16x16x32_bf16(ka0[kt], aq[qi][0], fzero, 0, 0, 0);
                st = __builtin_amdgcn_mfma_f32_16x16x32_bf16(ka1[kt], aq[qi][1], st, 0, 0, 0);
                float p0 = __builtin_amdgcn_exp2f(st[0] + mb0);
                float p1 = __builtin_amdgcn_exp2f(st[1] + mb1);
                float p2 = __builtin_amdgcn_exp2f(st[2] + mb2);
                float p3 = __builtin_amdgcn_exp2f(st[3] + mb3);
                uint2 pk; pk.x = pk2bf(p0, p1); pk.y = pk2bf(p2, p3);
                *(uint2*)(Pw + (qi * 2 + (kt >> 1)) * 512 + pidx) = pk;
            }
        }
    }

    // V fragments from LDS (must stay after P-write: live-range / spill)
    bf16x8 bv[2][4];
#pragma unroll
    for (int c = 0; c < 2; ++c)
#pragma unroll
        for (int nd = 0; nd < 4; ++nd)
            bv[c][nd] = *(const bf16x8*)(Vc + c * 2048 + nd * 512 + lane * 8);

    asm volatile("s_waitcnt lgkmcnt(0)" ::: "memory");

#pragma unroll
    for (int c = 0; c < 2; ++c)
#pragma unroll
        for (int qi = 0; qi < 2; ++qi) {
            bf16x8 ap = *(const bf16x8*)(Pw + (qi * 2 + c) * 512 + lane * 8);
#pragma unroll
            for (int nd = 0; nd < 4; ++nd)
                po[qi][nd] = __builtin_amdgcn_mfma_f32_16x16x32_bf16(ap, bv[c][nd], po[qi][nd], 0, 0, 0);
            pl[qi] = __builtin_amdgcn_mfma_f32_16x16x32_bf16(ap, vones, pl[qi], 0, 0, 0);
        }
}

__global__ __launch_bounds__(512, 4) void attn_kernel(
    const unsigned short* __restrict__ Qg, const unsigned short* __restrict__ Kf,
    const unsigned short* __restrict__ Vf, const int* __restrict__ mask,
    unsigned short* __restrict__ AO) {
    __shared__ __align__(16) unsigned short KsA[4096], KsB[4096];
    __shared__ __align__(16) unsigned short VsA[4096], VsB[4096];
    __shared__ __align__(16) unsigned short Pbuf[8][2048];

    const int tid = threadIdx.x;
    const int w = tid >> 6, lane = tid & 63;
    const int quad = lane >> 4, l16 = lane & 15;
    const int bid = blockIdx.x;
    const int bh = (bid & 7) * 8 + ((bid >> 6) & 7);
    const int qt = (bid >> 3) & 7;
    const int b = bh >> 4, h = bh & 15;
    const size_t bh_td = (size_t)bh * (2048 * 64);
    const int q0w = qt * 256 + w * 32;

    bf16x8 aq[2][2];
#pragma unroll
    for (int qi = 0; qi < 2; ++qi)
#pragma unroll
        for (int hh = 0; hh < 2; ++hh)
            aq[qi][hh] = *(const bf16x8*)(Qg + bh_td + (size_t)(q0w + qi * 16 + l16) * 64 + hh * 32 + quad * 8);

    const unsigned short* Kg = Kf + bh_td;
    const unsigned short* Vg = Vf + bh_td;
    const int* mrow = mask + b * 2048;

    bf16x8 vones;
#pragma unroll
    for (int i = 0; i < 8; ++i) vones[i] = (short)0x3F80;

    const f32x4 fzero = {0.f, 0.f, 0.f, 0.f};
    f32x4 po[2][4];
    f32x4 pl[2];
#pragma unroll
    for (int qi = 0; qi < 2; ++qi) {
        pl[qi] = fzero;
#pragma unroll
        for (int nd = 0; nd < 4; ++nd) po[qi][nd] = fzero;
    }

    // ---- whole-row mask precheck (one pass; hoists per-step mask logic) ----
    bool okl = true;
#pragma unroll
    for (int r = 0; r < 8; ++r) {
        int4 m4 = *(const int4*)(mrow + r * 256 + lane * 4);
        okl = okl && (m4.x != 0) && (m4.y != 0) && (m4.z != 0) && (m4.w != 0);
    }
    const bool all_ok = (__ballot(okl) == 0xFFFFFFFFFFFFFFFFull);

    gl_lds16(Kg + w * 512 + lane * 8, KsA + w * 512);
    gl_lds16(Vg + w * 512 + lane * 8, VsA + w * 512);
    asm volatile("s_waitcnt vmcnt(0)" ::: "memory");
    __syncthreads();

    if (all_ok) {
#pragma unroll 1
        for (int k0 = 0; k0 < 2048; k0 += 128) {
            attn_step_staged<false>(k0, KsA, VsA, KsB, VsB, k0 + 64,
                                    Kg, Vg, Pbuf[w], aq, vones, po, pl, mrow, w, lane, quad, l16);
            asm volatile("s_waitcnt vmcnt(0)" ::: "memory");
            __syncthreads();
            attn_step_staged<false>(k0 + 64, KsB, VsB, KsA, VsA, (k0 + 128) & 2047,
                                    Kg, Vg, Pbuf[w], aq, vones, po, pl, mrow, w, lane, quad, l16);
            asm volatile("s_waitcnt vmcnt(0)" ::: "memory");
            __syncthreads();
        }
    } else {
#pragma unroll 1
        for (int k0 = 0; k0 < 2048; k0 += 128) {
            attn_step_staged<true>(k0, KsA, VsA, KsB, VsB, k0 + 64,
                                   Kg, Vg, Pbuf[w], aq, vones, po, pl, mrow, w, lane, quad, l16);
            asm volatile("s_waitcnt vmcnt(0)" ::: "memory");
            __syncthreads();
            attn_step_staged<true>(k0 + 64, KsB, VsB, KsA, VsA, (k0 + 128) & 2047,
                                   Kg, Vg, Pbuf[w], aq, vones, po, pl, mrow, w, lane, quad, l16);
            asm volatile("s_waitcnt vmcnt(0)" ::: "memory");
            __syncthreads();
        }
    }

    // ---- epilogue: pl has same C layout as po -> direct normalize & store ----
#pragma unroll
    for (int qi = 0; qi < 2; ++qi)
#pragma unroll
        for (int r = 0; r < 4; ++r) {
            float linv = __builtin_amdgcn_rcpf(pl[qi][r]);
            int q = q0w + qi * 16 + quad * 4 + r;
            size_t ob = (size_t)(b * 2048 + q) * 1024 + h * 64;
#pragma unroll
            for (int nd = 0; nd < 4; ++nd)
                AO[ob + nd * 16 + l16] = f2bf(po[qi][nd][r] * linv);
        }
}

extern "C" void kernel_launch(void* const* d_in, const int* in_sizes, int n_in,
                              void* d_out, int out_size, void* d_ws, size_t ws_size,
                              hipStream_t stream) {
    const float* hs  = (const float*)d_in[0];
    const int* mask  = (const int*)d_in[1];
    const float* Wq  = (const float*)d_in[2];
    const float* Wk  = (const float*)d_in[3];
    const float* Wv  = (const float*)d_in[4];
    const float* Wo  = (const float*)d_in[5];
    const float* bo  = (const float*)d_in[6];
    float* out = (float*)d_out;

    char* ws = (char*)d_ws;
    unsigned short* hs_bf = (unsigned short*)(ws);                  // 16 MB
    unsigned short* wqkv  = (unsigned short*)(ws + 16777216);       // 6 MB
    unsigned short* wo_t  = (unsigned short*)(ws + 23068672);       // 2 MB
    unsigned short* Qg    = (unsigned short*)(ws + 25165824);       // 16 MB
    unsigned short* Kf    = (unsigned short*)(ws + 41943040);       // 16 MB
    unsigned short* Vf    = (unsigned short*)(ws + 58720256);       // 16 MB
    unsigned short* AO    = (unsigned short*)(ws + 75497472);       // 16 MB

    cvtw_kernel<<<9216, 256, 0, stream>>>((const float4*)hs, (ushort4*)hs_bf,
                                          Wq, Wk, Wv, Wo, wqkv, wo_t);
    gemm_qkv_kernel<<<768, 512, 0, stream>>>(hs_bf, wqkv, Qg, Kf, Vf);
    attn_kernel<<<512, 512, 0, stream>>>(Qg, Kf, Vf, mask, AO);
    gemm_out_kernel<<<256, 512, 0, stream>>>(AO, wo_t, bo, out);
}